// Round 1
// baseline (730.899 us; speedup 1.0000x reference)
//
#include <hip/hip_runtime.h>

typedef unsigned short u16;
typedef unsigned int u32;
typedef __attribute__((ext_vector_type(8))) __bf16 bf16x8;
typedef __attribute__((ext_vector_type(4))) float f32x4;

#define E_TILE 64
#define KP 160      // padded K: 128 h + 1 bias-one + 31 zeros
#define KL 168      // LDS row stride in u16 (336B = 21*16B, 2-way bank alias only)
#define NCHUNK 64   // W2T rows staged per LDS chunk
#define WNTOT 2304

#define A0C   0.14433756729740643f   /* sqrt(1/48) */
#define A0IS3 0.08333333333333333f   /* A0/sqrt(3) = 1/12 */
#define A1IS3 0.14433756729740643f   /* (1/4)/sqrt(3) */

__device__ inline u16 f2bf(float f) {
    union { float f; u32 u; } v; v.f = f;
    u32 u = v.u;
    return (u16)((u + 0x7FFFu + ((u >> 16) & 1u)) >> 16);  // RNE
}
__device__ inline float bf2f(u16 s) {
    union { u32 u; float f; } v; v.u = ((u32)s) << 16; return v.f;
}

// Build W2T[n][k] bf16: k<128 -> W2[k][n]; k==128 -> b2[n]; else 0.
__global__ void prep_w2t(const float* __restrict__ w2, const float* __restrict__ b2,
                         u16* __restrict__ w2t) {
    int idx = blockIdx.x * 256 + threadIdx.x;
    if (idx >= WNTOT * KP) return;
    int n = idx / KP, k = idx - n * KP;
    float v = 0.f;
    if (k < 128) v = w2[k * WNTOT + n];
    else if (k == 128) v = b2[n];
    w2t[idx] = f2bf(v);
}

__global__ void count_k(const int* __restrict__ src, int E, int* __restrict__ cnt) {
    int i = blockIdx.x * 256 + threadIdx.x;
    if (i < E) atomicAdd(&cnt[src[i]], 1);
}

__global__ void finalize_k(float* __restrict__ out, const int* __restrict__ cnt, int total) {
    int i = blockIdx.x * 256 + threadIdx.x;
    if (i >= total) return;
    float c = (float)cnt[i / 80];
    out[i] /= fmaxf(c, 1.0f);
}

__global__ __launch_bounds__(256, 2)
void tpcl_main(const float* __restrict__ node_attr,
               const int* __restrict__ edge_index,
               const float* __restrict__ edge_attr,
               const float* __restrict__ edge_sh,
               const float* __restrict__ fc_w1,
               const float* __restrict__ fc_b1,
               const u16* __restrict__ w2t,
               float* __restrict__ out,
               int N, int E)
{
    __shared__ u16 h_lds[E_TILE][KL];     // A: h (bf16), K-padded
    __shared__ u16 w2_lds[NCHUNK][KL];    // B chunk: W2T rows (also reused for ea staging)
    __shared__ u16 L1s[E_TILE][32];       // A0*sh0*x0[u]
    __shared__ u16 L4s[E_TILE][16];       // A0IS3*t[u]
    __shared__ u16 X0s[E_TILE][32];       // x0[u]
    __shared__ u16 X1s[E_TILE][48];       // x1[u][m]
    __shared__ float SHs[E_TILE][4];      // A1IS3*sh1[0..2], A1IS3*sh0
    __shared__ int SRCs[E_TILE];

    const int tid = threadIdx.x;
    const int ebase = blockIdx.x * E_TILE;

    // ---- Phase 0: stage edge_attr tile (bf16) into w2_lds area ----
    u16* ea_lds = &w2_lds[0][0];          // 64*32 u16 = 4KB, fits
    for (int i = tid; i < E_TILE * 32; i += 256) {
        int e = i >> 5, c = i & 31;
        int eg = ebase + e;
        float v = (eg < E) ? edge_attr[(size_t)eg * 32 + c] : 0.f;
        ea_lds[e * 32 + c] = f2bf(v);
    }

    // ---- Phase 0b: gather node_attr[dst], build coefficient tables ----
    {
        int e = tid >> 2, t4 = tid & 3;   // 4 threads per edge
        int eg = ebase + e;
        bool valid = eg < E;
        int srci = 0, dst = 0;
        float sh0 = 0.f, s1a = 0.f, s1b = 0.f, s1c = 0.f;
        if (valid) {
            srci = edge_index[eg];
            dst  = edge_index[E + eg];
            sh0  = edge_sh[(size_t)eg * 4 + 0];
            s1a  = edge_sh[(size_t)eg * 4 + 1];
            s1b  = edge_sh[(size_t)eg * 4 + 2];
            s1c  = edge_sh[(size_t)eg * 4 + 3];
        }
        if (t4 == 0) {
            SRCs[e] = srci;
            SHs[e][0] = A1IS3 * s1a;
            SHs[e][1] = A1IS3 * s1b;
            SHs[e][2] = A1IS3 * s1c;
            SHs[e][3] = A1IS3 * sh0;
        }
        const float* na = node_attr + (size_t)dst * 80;
        float l1c = A0C * sh0;
#pragma unroll
        for (int q = 0; q < 8; ++q) {
            int u = t4 * 8 + q;
            float x = valid ? na[u] : 0.f;
            X0s[e][u] = f2bf(x);
            L1s[e][u] = f2bf(l1c * x);
        }
#pragma unroll
        for (int q = 0; q < 4; ++q) {
            int u = t4 * 4 + q;
            float xa = valid ? na[32 + u * 3 + 0] : 0.f;
            float xb = valid ? na[32 + u * 3 + 1] : 0.f;
            float xc = valid ? na[32 + u * 3 + 2] : 0.f;
            X1s[e][u * 3 + 0] = f2bf(xa);
            X1s[e][u * 3 + 1] = f2bf(xb);
            X1s[e][u * 3 + 2] = f2bf(xc);
            float t = xa * s1a + xb * s1b + xc * s1c;
            L4s[e][u] = f2bf(A0IS3 * t);
        }
    }
    __syncthreads();

    // ---- Phase 1: h = relu(ea @ W1 + b1) -> h_lds (bf16) ----
    {
        int j = tid & 127;
        int e0 = tid >> 7;                // 0..1
        float w1col[32];
#pragma unroll
        for (int i = 0; i < 32; ++i) w1col[i] = fc_w1[i * 128 + j];
        float b = fc_b1[j];
        for (int rep = 0; rep < 32; ++rep) {
            int e = e0 + rep * 2;
            const u16* ea = &ea_lds[e * 32];
            float acc = b;
#pragma unroll
            for (int i = 0; i < 32; ++i) acc += bf2f(ea[i]) * w1col[i];
            h_lds[e][j] = f2bf(fmaxf(acc, 0.f));
        }
        // K-pad: k=128 -> 1.0 (bias row), k=129..159 -> 0
        for (int i = tid; i < E_TILE * 32; i += 256) {
            int e = i >> 5, k = 128 + (i & 31);
            h_lds[e][k] = (k == 128) ? (u16)0x3F80 : (u16)0;
        }
    }
    __syncthreads();

    // ---- A fragments: reused across ALL N-tiles ----
    const int lane = tid & 63;
    const int wave = tid >> 6;
    const int mrow = wave * 16 + (lane & 15);
    const int ko = (lane >> 4) * 8;
    bf16x8 afrag[5];
#pragma unroll
    for (int kk = 0; kk < 5; ++kk)
        afrag[kk] = *(const bf16x8*)&h_lds[mrow][kk * 32 + ko];

    float o0[2][4] = {};   // out0[v], out0[v+16]
    float q2[4] = {};
    float q3[3][4] = {};
    const int erow0 = wave * 16 + ((lane >> 4) << 2);   // C rows: erow0 + reg

    // ---- Phase 2: 36 chunks x 4 N-tiles x 5 K-steps ----
    for (int ch = 0; ch < 36; ++ch) {
        __syncthreads();
        {   // stage 64 W2T rows (160 u16 each) -> w2_lds
            int nb = ch * NCHUNK;
            for (int i = tid; i < NCHUNK * 20; i += 256) {
                int r = i / 20, c = i % 20;
                uint4 v = *(const uint4*)&w2t[(size_t)(nb + r) * KP + c * 8];
                *(uint4*)&w2_lds[r][c * 8] = v;
            }
        }
        __syncthreads();

#pragma unroll
        for (int nt = 0; nt < 4; ++nt) {
            int nrow = nt * 16 + (lane & 15);
            f32x4 acc = {0.f, 0.f, 0.f, 0.f};
#pragma unroll
            for (int kk = 0; kk < 5; ++kk) {
                bf16x8 bfr = *(const bf16x8*)&w2_lds[nrow][kk * 32 + ko];
                acc = __builtin_amdgcn_mfma_f32_16x16x32_bf16(afrag[kk], bfr, acc, 0, 0, 0);
            }
            int gnt = ch * 4 + nt;   // global 16-col tile id, 0..143
            if (gnt < 64) {          // w1: u = gnt>>1, vhalf = gnt&1, coeff L1
                int u = gnt >> 1, half = gnt & 1;
#pragma unroll
                for (int r = 0; r < 4; ++r)
                    o0[half][r] += bf2f(L1s[erow0 + r][u]) * acc[r];
            } else if (gnt < 96) {   // w2: coeff x0[u]
                int u = gnt - 64;
#pragma unroll
                for (int r = 0; r < 4; ++r)
                    q2[r] += bf2f(X0s[erow0 + r][u]) * acc[r];
            } else if (gnt < 112) {  // w3: coeff x1[u][m], m=0..2
                int u = gnt - 96;
#pragma unroll
                for (int r = 0; r < 4; ++r) {
                    float a = acc[r];
                    q3[0][r] += bf2f(X1s[erow0 + r][u * 3 + 0]) * a;
                    q3[1][r] += bf2f(X1s[erow0 + r][u * 3 + 1]) * a;
                    q3[2][r] += bf2f(X1s[erow0 + r][u * 3 + 2]) * a;
                }
            } else {                 // w4: coeff L4
                int idx = gnt - 112;
                int u = idx >> 1, half = idx & 1;
#pragma unroll
                for (int r = 0; r < 4; ++r)
                    o0[half][r] += bf2f(L4s[erow0 + r][u]) * acc[r];
            }
        }
    }

    // ---- Phase 3: atomic scatter by edge_src ----
    {
        int v = lane & 15;
#pragma unroll
        for (int r = 0; r < 4; ++r) {
            int e = erow0 + r;
            int eg = ebase + e;
            if (eg < E) {
                int s = SRCs[e];
                float* op = out + (size_t)s * 80;
                float s0 = SHs[e][0], s1 = SHs[e][1], s2 = SHs[e][2], g = SHs[e][3];
                unsafeAtomicAdd(&op[v],        o0[0][r]);
                unsafeAtomicAdd(&op[16 + v],   o0[1][r]);
                unsafeAtomicAdd(&op[32 + v * 3 + 0], q2[r] * s0 + g * q3[0][r]);
                unsafeAtomicAdd(&op[32 + v * 3 + 1], q2[r] * s1 + g * q3[1][r]);
                unsafeAtomicAdd(&op[32 + v * 3 + 2], q2[r] * s2 + g * q3[2][r]);
            }
        }
    }
}

extern "C" void kernel_launch(void* const* d_in, const int* in_sizes, int n_in,
                              void* d_out, int out_size, void* d_ws, size_t ws_size,
                              hipStream_t stream) {
    const float* node_attr = (const float*)d_in[0];
    const int*   edge_index = (const int*)d_in[1];
    const float* edge_attr = (const float*)d_in[2];
    const float* edge_sh   = (const float*)d_in[3];
    const float* fc_w1     = (const float*)d_in[4];
    const float* fc_b1     = (const float*)d_in[5];
    const float* fc_w2     = (const float*)d_in[6];
    const float* fc_b2     = (const float*)d_in[7];
    int N = in_sizes[0] / 80;
    int E = in_sizes[1] / 2;
    float* out = (float*)d_out;

    int* cnt = (int*)d_ws;
    size_t cnt_bytes = ((size_t)N * 4 + 127) & ~(size_t)127;
    u16* w2t = (u16*)((char*)d_ws + cnt_bytes);

    hipMemsetAsync(out, 0, (size_t)N * 80 * 4, stream);
    hipMemsetAsync(cnt, 0, (size_t)N * 4, stream);

    int prep_total = WNTOT * KP;
    prep_w2t<<<(prep_total + 255) / 256, 256, 0, stream>>>(fc_w2, fc_b2, w2t);
    count_k<<<(E + 255) / 256, 256, 0, stream>>>(edge_index, E, cnt);
    tpcl_main<<<(E + E_TILE - 1) / E_TILE, 256, 0, stream>>>(
        node_attr, edge_index, edge_attr, edge_sh, fc_w1, fc_b1, w2t, out, N, E);
    finalize_k<<<(N * 80 + 255) / 256, 256, 0, stream>>>(out, cnt, N * 80);
}